// Round 3
// baseline (294.378 us; speedup 1.0000x reference)
//
#include <hip/hip_runtime.h>

#define NTOK 65536
#define DIM 256
#define KC 1024
#define EPS 0.08f

typedef __attribute__((ext_vector_type(8))) _Float16 f16x8;
typedef __attribute__((ext_vector_type(4))) float f32x4;

static __device__ __forceinline__ unsigned short f16bits(float f) {
  _Float16 h = (_Float16)f;
  return __builtin_bit_cast(unsigned short, h);
}
static __device__ __forceinline__ void gload16(const void* g, void* l) {
  __builtin_amdgcn_global_load_lds(
      (const __attribute__((address_space(1))) unsigned int*)g,
      (__attribute__((address_space(3))) unsigned int*)l, 16, 0, 0);
}

// ---- fp32 -> fp16 (pre-swizzled global layout) + row sum-of-squares ----
// Layout: row r (512 B of f16), K-slice s (128 B), within-slice byte b holds
// k = s*64 + (b ^ ((r&7)<<4))/2. Wave per row.
__global__ __launch_bounds__(256) void vq_split(const float* __restrict__ in,
                                                unsigned short* __restrict__ oh,
                                                float* __restrict__ sq) {
  const int w = threadIdx.x >> 6, l = threadIdx.x & 63;
  const int t = blockIdx.x * 4 + w;
  const float4 v = *reinterpret_cast<const float4*>(&in[t * DIM + l * 4]);
  ushort4 o;
  o.x = f16bits(v.x); o.y = f16bits(v.y); o.z = f16bits(v.z); o.w = f16bits(v.w);
  const int addr = t * 512 + ((l >> 4) << 7) + ((((l & 15) * 8) ^ ((t & 7) << 4)));
  *reinterpret_cast<ushort4*>((char*)oh + addr) = o;
  float s = v.x * v.x + v.y * v.y + v.z * v.z + v.w * v.w;
#pragma unroll
  for (int o2 = 32; o2 > 0; o2 >>= 1) s += __shfl_down(s, o2, 64);
  if (l == 0) sq[t] = s;
}

// ---- fp16 MFMA distance GEMM + argmin(+second) ----
__global__ __launch_bounds__(256, 4) void vq_mfma_argmin(
    const unsigned short* __restrict__ xg, const unsigned short* __restrict__ eg,
    const float* __restrict__ esq, float* __restrict__ outIdxF,
    float* __restrict__ bestDist, int* __restrict__ fixCount,
    int* __restrict__ fixList) {
  __shared__ unsigned short xs[128 * 64];
  __shared__ unsigned short es[128 * 64];
  __shared__ float redB[2][128];
  __shared__ float redS[2][128];
  __shared__ int   redI[2][128];

  const int tid = threadIdx.x, lane = tid & 63, w = tid >> 6;
  const int wr = w >> 1, wc = w & 1;
  const int tokBase = blockIdx.x * 128;
  const int col = lane & 15, kq = lane >> 4;
  const int srow = lane >> 3;          // staging: 8 lanes per 128-B row
  const int scol = (lane & 7) * 8;     // staging: ushort offset within row

  float best[4][4], second[4][4];
  int bidx[4][4];
#pragma unroll
  for (int mi = 0; mi < 4; ++mi)
#pragma unroll
    for (int r = 0; r < 4; ++r) {
      best[mi][r] = 3.4e38f; second[mi][r] = 3.4e38f; bidx[mi][r] = 0;
    }

  for (int ct = 0; ct < 8; ++ct) {
    f32x4 acc[4][4];
#pragma unroll
    for (int mi = 0; mi < 4; ++mi)
#pragma unroll
      for (int nj = 0; nj < 4; ++nj) acc[mi][nj] = (f32x4){0.f, 0.f, 0.f, 0.f};

    for (int kt = 0; kt < 4; ++kt) {
      __syncthreads();  // previous tile consumed
#pragma unroll
      for (int q = 0; q < 4; ++q) {
        const int r0 = (w * 4 + q) * 8;  // 8-row stripe, wave-uniform
        const int xr = tokBase + r0 + srow;
        const int er = ct * 128 + r0 + srow;
        gload16(&xg[xr * DIM + kt * 64 + scol], &xs[r0 * 64]);
        gload16(&eg[er * DIM + kt * 64 + scol], &es[r0 * 64]);
      }
      __syncthreads();  // tiles ready (drains vmcnt)

#pragma unroll
      for (int ks = 0; ks < 2; ++ks) {
        const int kb = ks * 64 + kq * 16;  // byte offset within 128-B row
        f16x8 a[4], b[4];
#pragma unroll
        for (int mi = 0; mi < 4; ++mi) {
          const int rr = wr * 64 + mi * 16 + col;
          a[mi] = *reinterpret_cast<const f16x8*>(
              (const char*)xs + rr * 128 + (kb ^ ((col & 7) << 4)));
        }
#pragma unroll
        for (int nj = 0; nj < 4; ++nj) {
          const int rr = wc * 64 + nj * 16 + col;
          b[nj] = *reinterpret_cast<const f16x8*>(
              (const char*)es + rr * 128 + (kb ^ ((col & 7) << 4)));
        }
#pragma unroll
        for (int mi = 0; mi < 4; ++mi)
#pragma unroll
          for (int nj = 0; nj < 4; ++nj)
            acc[mi][nj] = __builtin_amdgcn_mfma_f32_16x16x32_f16(
                a[mi], b[nj], acc[mi][nj], 0, 0, 0);
      }
    }

    // distances for this 128-code chunk; codes ascend per lane over (ct, nj)
#pragma unroll
    for (int nj = 0; nj < 4; ++nj) {
      const int code = ct * 128 + wc * 64 + nj * 16 + col;
      const float sqv = esq[code];
#pragma unroll
      for (int mi = 0; mi < 4; ++mi)
#pragma unroll
        for (int r = 0; r < 4; ++r) {
          const float d = fmaf(-2.f, acc[mi][nj][r], sqv);
          if (d < best[mi][r]) {
            second[mi][r] = best[mi][r];
            best[mi][r] = d;
            bidx[mi][r] = code;
          } else if (d < second[mi][r]) {
            second[mi][r] = d;
          }
        }
    }
  }

  // cross-lane reduce over the 16 code-columns (xor masks 1,2,4,8)
#pragma unroll
  for (int mi = 0; mi < 4; ++mi)
#pragma unroll
    for (int r = 0; r < 4; ++r) {
      float b = best[mi][r], s2 = second[mi][r];
      int bi = bidx[mi][r];
#pragma unroll
      for (int m = 1; m <= 8; m <<= 1) {
        const float ob = __shfl_xor(b, m, 64);
        const float os = __shfl_xor(s2, m, 64);
        const int   oi = __shfl_xor(bi, m, 64);
        s2 = fminf(fminf(s2, os), fmaxf(b, ob));
        if (ob < b || (ob == b && oi < bi)) { b = ob; bi = oi; }
      }
      if (col == 0) {
        const int row = wr * 64 + mi * 16 + kq * 4 + r;
        redB[wc][row] = b; redS[wc][row] = s2; redI[wc][row] = bi;
      }
    }
  __syncthreads();
  if (tid < 128) {
    const float b0 = redB[0][tid], b1 = redB[1][tid];
    const float s0 = redS[0][tid], s1 = redS[1][tid];
    const int i0 = redI[0][tid], i1 = redI[1][tid];
    const float s2 = fminf(fminf(s0, s1), fmaxf(b0, b1));
    float b; int bi;
    if (b1 < b0 || (b1 == b0 && i1 < i0)) { b = b1; bi = i1; } else { b = b0; bi = i0; }
    const int t = tokBase + tid;
    outIdxF[t] = (float)bi;
    bestDist[t] = b;
    if (s2 - b < EPS) {
      const int p = atomicAdd(fixCount, 1);
      fixList[p] = t;
    }
  }
}

// ---- exact fp32 rescan for near-tie tokens ----
__global__ __launch_bounds__(256) void vq_fixup(
    const float* __restrict__ x, const float* __restrict__ e,
    const float* __restrict__ esq, const int* __restrict__ fixCount,
    const int* __restrict__ fixList, float* __restrict__ outIdxF,
    float* __restrict__ bestDist) {
  const int n = *fixCount;
  __shared__ float xrow[256];
  __shared__ float rv[4];
  __shared__ int ri[4];
  const int tid = threadIdx.x;
  for (int it = blockIdx.x; it < n; it += gridDim.x) {
    const int t = fixList[it];
    __syncthreads();
    if (tid < 64) ((float4*)xrow)[tid] = ((const float4*)&x[t * DIM])[tid];
    __syncthreads();
    float bv = 3.4e38f; int bi = 0;
    for (int c = tid; c < KC; c += 256) {
      float s = 0.f;
#pragma unroll
      for (int d = 0; d < DIM; d += 4) {
        const float4 ev = *(const float4*)&e[c * DIM + d];
        s = fmaf(xrow[d], ev.x, s);
        s = fmaf(xrow[d + 1], ev.y, s);
        s = fmaf(xrow[d + 2], ev.z, s);
        s = fmaf(xrow[d + 3], ev.w, s);
      }
      const float dist = fmaf(-2.f, s, esq[c]);
      if (dist < bv) { bv = dist; bi = c; }
    }
#pragma unroll
    for (int m = 1; m <= 32; m <<= 1) {
      const float ob = __shfl_xor(bv, m, 64);
      const int oi = __shfl_xor(bi, m, 64);
      if (ob < bv || (ob == bv && oi < bi)) { bv = ob; bi = oi; }
    }
    const int lane = tid & 63, wv = tid >> 6;
    if (lane == 0) { rv[wv] = bv; ri[wv] = bi; }
    __syncthreads();
    if (tid == 0) {
      float fb = rv[0]; int fi = ri[0];
      for (int k = 1; k < 4; ++k)
        if (rv[k] < fb || (rv[k] == fb && ri[k] < fi)) { fb = rv[k]; fi = ri[k]; }
      outIdxF[t] = (float)fi;
      bestDist[t] = fb;
    }
  }
}

// ---- histogram ----
__global__ __launch_bounds__(256) void vq_hist(const float* __restrict__ idxF,
                                               int* __restrict__ hist) {
  atomicAdd(&hist[(int)idxF[blockIdx.x * 256 + threadIdx.x]], 1);
}

// ---- gather (wave per token) + loss partials from xsq+bestDist ----
__global__ __launch_bounds__(256) void vq_gather(
    const float* __restrict__ e, const float* __restrict__ idxF,
    const float* __restrict__ xsq, const float* __restrict__ bestDist,
    float* __restrict__ outQ, float* __restrict__ partial) {
  const int w = threadIdx.x >> 6, l = threadIdx.x & 63;
  const int t = blockIdx.x * 4 + w;
  const int id = (int)idxF[t];
  const float4 q = *reinterpret_cast<const float4*>(&e[id * DIM + l * 4]);
  *reinterpret_cast<float4*>(&outQ[t * DIM + l * 4]) = q;
  __shared__ float ls[4];
  if (l == 0) ls[w] = xsq[t] + bestDist[t];
  __syncthreads();
  if (threadIdx.x == 0)
    partial[blockIdx.x] = ls[0] + ls[1] + ls[2] + ls[3];
}

// ---- final scalars ----
__global__ __launch_bounds__(1024) void vq_final(
    const int* __restrict__ hist, const float* __restrict__ partial,
    float* __restrict__ outLoss, float* __restrict__ outPerp) {
  const int tid = threadIdx.x;
  float ls = 0.f;
#pragma unroll
  for (int i = 0; i < 16; ++i) ls += partial[tid + i * 1024];
  const float p = (float)hist[tid] * (1.f / 65536.f);
  float ent = p * logf(p + 1e-10f);
#pragma unroll
  for (int o = 32; o > 0; o >>= 1) {
    ls += __shfl_down(ls, o, 64);
    ent += __shfl_down(ent, o, 64);
  }
  __shared__ float lbuf[16], ebuf[16];
  const int lane = tid & 63, wv = tid >> 6;
  if (lane == 0) { lbuf[wv] = ls; ebuf[wv] = ent; }
  __syncthreads();
  if (tid == 0) {
    float L = 0.f, E = 0.f;
    for (int i = 0; i < 16; ++i) { L += lbuf[i]; E += ebuf[i]; }
    *outLoss = 0.25f * (L / 16777216.f);
    *outPerp = expf(-E);
  }
}

extern "C" void kernel_launch(void* const* d_in, const int* in_sizes, int n_in,
                              void* d_out, int out_size, void* d_ws, size_t ws_size,
                              hipStream_t stream) {
  const float* x = (const float*)d_in[0];  // [65536, 256]
  const float* e = (const float*)d_in[1];  // [1024, 256]
  float* out = (float*)d_out;
  float* outQ = out;                 // 16777216 floats
  float* outLoss = out + 16777216;
  float* outPerp = out + 16777217;
  float* outIdxF = out + 16777218;   // 65536 floats

  // x_f16 (swizzled) lives in d_out's quantized region; consumed by argmin
  // before vq_gather overwrites outQ.
  unsigned short* x_f16 = (unsigned short*)d_out;  // 33.5 MB

  char* ws = (char*)d_ws;
  int*   hist     = (int*)ws;                    // 4096 B
  float* partial  = (float*)(ws + 4096);         // 65536 B (16384 floats)
  float* esq      = (float*)(ws + 69632);        // 4096 B
  float* xsq      = (float*)(ws + 73728);        // 262144 B
  float* bestDist = (float*)(ws + 335872);       // 262144 B
  int*   fixCount = (int*)(ws + 598016);         // 16 B
  int*   fixList  = (int*)(ws + 598032);         // 262144 B
  unsigned short* e_f16 = (unsigned short*)(ws + 860176);  // 524288 B
  // total ws use ~1.39 MB

  hipMemsetAsync(hist, 0, KC * sizeof(int), stream);
  hipMemsetAsync(fixCount, 0, sizeof(int), stream);
  vq_split<<<NTOK / 4, 256, 0, stream>>>(x, x_f16, xsq);
  vq_split<<<KC / 4, 256, 0, stream>>>(e, e_f16, esq);
  vq_mfma_argmin<<<NTOK / 128, 256, 0, stream>>>(x_f16, e_f16, esq, outIdxF,
                                                 bestDist, fixCount, fixList);
  vq_fixup<<<256, 256, 0, stream>>>(x, e, esq, fixCount, fixList, outIdxF, bestDist);
  vq_hist<<<NTOK / 256, 256, 0, stream>>>(outIdxF, hist);
  vq_gather<<<NTOK / 4, 256, 0, stream>>>(e, outIdxF, xsq, bestDist, outQ, partial);
  vq_final<<<1, 1024, 0, stream>>>(hist, partial, outLoss, outPerp);
}

// Round 4
// 204.749 us; speedup vs baseline: 1.4377x; 1.4377x over previous
//
#include <hip/hip_runtime.h>

#define NTOK 65536
#define DIM 256
#define KC 1024
#define EPS 0.08f

typedef __attribute__((ext_vector_type(8))) _Float16 f16x8;
typedef __attribute__((ext_vector_type(4))) float f32x4;

static __device__ __forceinline__ unsigned short f16bits(float f) {
  _Float16 h = (_Float16)f;
  return __builtin_bit_cast(unsigned short, h);
}
static __device__ __forceinline__ void gload16(const void* g, void* l) {
  __builtin_amdgcn_global_load_lds(
      (const __attribute__((address_space(1))) unsigned int*)g,
      (__attribute__((address_space(3))) unsigned int*)l, 16, 0, 0);
}

// ---- e: fp32 -> fp16 swizzled global + esq; zero hist/fixCount ----
// Global image per row: 512 B = 4 slices of 128 B; within slice byte
// b holds k with b = ((k&63)*2) ^ ((row&7)<<4), slice = k>>6.
__global__ __launch_bounds__(256) void vq_prep_e(const float* __restrict__ e,
                                                 unsigned short* __restrict__ eg,
                                                 float* __restrict__ esq,
                                                 int* __restrict__ hist,
                                                 int* __restrict__ fixCount) {
  const int w = threadIdx.x >> 6, l = threadIdx.x & 63;
  const int t = blockIdx.x * 4 + w;
  const float4 v = *reinterpret_cast<const float4*>(&e[t * DIM + l * 4]);
  ushort4 o;
  o.x = f16bits(v.x); o.y = f16bits(v.y); o.z = f16bits(v.z); o.w = f16bits(v.w);
  const int addr = t * 512 + ((l >> 4) << 7) + ((((l & 15) * 8) ^ ((t & 7) << 4)));
  *reinterpret_cast<ushort4*>((char*)eg + addr) = o;
  float s = v.x * v.x + v.y * v.y + v.z * v.z + v.w * v.w;
#pragma unroll
  for (int o2 = 32; o2 > 0; o2 >>= 1) s += __shfl_down(s, o2, 64);
  if (l == 0) esq[t] = s;
  if (blockIdx.x < 4) hist[blockIdx.x * 256 + threadIdx.x] = 0;
  if (blockIdx.x == 0 && threadIdx.x == 0) *fixCount = 0;
}

// ---- fused: x-stage + fp16 MFMA distances + argmin + hist + gather ----
__global__ __launch_bounds__(256, 2) void vq_argmin_fused(
    const float* __restrict__ x, const unsigned short* __restrict__ eg,
    const float* __restrict__ e, const float* __restrict__ esq,
    float* __restrict__ outIdxF, float* __restrict__ outQ,
    float* __restrict__ bestDist, float* __restrict__ xsq,
    int* __restrict__ hist, int* __restrict__ fixCount,
    int* __restrict__ fixList) {
  __shared__ unsigned short xs[128 * 256];  // 64 KB, full-K x tile (swizzled)
  __shared__ unsigned short es[128 * 64];   // 16 KB e tile; overlaid later

  const int tid = threadIdx.x, lane = tid & 63, w = tid >> 6;
  const int wr = w >> 1, wc = w & 1;
  const int tokBase = blockIdx.x * 128;
  const int col = lane & 15, kq = lane >> 4;

  // -- prologue: stage x[128][256] fp32 -> f16 swizzled LDS; per-row xsq --
  {
    const float4* xb = reinterpret_cast<const float4*>(&x[tokBase * DIM]);
    for (int c = 0; c < 32; ++c) {
      const int r = c * 4 + w;  // wave w owns rows r == w (mod 4)
      const float4 v = xb[c * 256 + tid];
      ushort4 o;
      o.x = f16bits(v.x); o.y = f16bits(v.y); o.z = f16bits(v.z); o.w = f16bits(v.w);
      const int addr =
          r * 512 + ((lane >> 4) << 7) + ((((lane & 15) * 8) ^ ((r & 7) << 4)));
      *reinterpret_cast<ushort4*>((char*)xs + addr) = o;
      float s = v.x * v.x + v.y * v.y + v.z * v.z + v.w * v.w;
#pragma unroll
      for (int o2 = 32; o2 > 0; o2 >>= 1) s += __shfl_down(s, o2, 64);
      if (lane == 0) xsq[tokBase + r] = s;
    }
  }

  float best[4][4], second[4][4];
  int bidx[4][4];
#pragma unroll
  for (int mi = 0; mi < 4; ++mi)
#pragma unroll
    for (int r = 0; r < 4; ++r) {
      best[mi][r] = 3.4e38f; second[mi][r] = 3.4e38f; bidx[mi][r] = 0;
    }

  for (int ct = 0; ct < 8; ++ct) {
    f32x4 acc[4][4];
#pragma unroll
    for (int mi = 0; mi < 4; ++mi)
#pragma unroll
      for (int nj = 0; nj < 4; ++nj) acc[mi][nj] = (f32x4){0.f, 0.f, 0.f, 0.f};

    for (int kt = 0; kt < 4; ++kt) {
      __syncthreads();  // previous e-tile consumed (and prologue ds_writes done)
#pragma unroll
      for (int q = 0; q < 4; ++q) {
        const int r0 = (w * 4 + q) * 8;  // wave-uniform 8-row stripe
        const int er = ct * 128 + r0 + (lane >> 3);
        gload16(&eg[er * DIM + kt * 64 + (lane & 7) * 8], &es[r0 * 64]);
      }
      __syncthreads();  // e-tile ready (drains vmcnt)

#pragma unroll
      for (int ks = 0; ks < 2; ++ks) {
        const int kb = ks * 64 + kq * 16;  // byte offset within 128-B slice
        f16x8 a[4], b[4];
#pragma unroll
        for (int mi = 0; mi < 4; ++mi) {
          const int rr = wr * 64 + mi * 16 + col;
          a[mi] = *reinterpret_cast<const f16x8*>(
              (const char*)xs + rr * 512 + kt * 128 + (kb ^ ((col & 7) << 4)));
        }
#pragma unroll
        for (int nj = 0; nj < 4; ++nj) {
          const int rr = wc * 64 + nj * 16 + col;
          b[nj] = *reinterpret_cast<const f16x8*>(
              (const char*)es + rr * 128 + (kb ^ ((col & 7) << 4)));
        }
#pragma unroll
        for (int mi = 0; mi < 4; ++mi)
#pragma unroll
          for (int nj = 0; nj < 4; ++nj)
            acc[mi][nj] = __builtin_amdgcn_mfma_f32_16x16x32_f16(
                a[mi], b[nj], acc[mi][nj], 0, 0, 0);
      }
    }

    // distances for this 128-code chunk; codes ascend per lane over (ct, nj)
#pragma unroll
    for (int nj = 0; nj < 4; ++nj) {
      const int code = ct * 128 + wc * 64 + nj * 16 + col;
      const float sqv = esq[code];
#pragma unroll
      for (int mi = 0; mi < 4; ++mi)
#pragma unroll
        for (int r = 0; r < 4; ++r) {
          const float d = fmaf(-2.f, acc[mi][nj][r], sqv);
          if (d < best[mi][r]) {
            second[mi][r] = best[mi][r];
            best[mi][r] = d;
            bidx[mi][r] = code;
          } else if (d < second[mi][r]) {
            second[mi][r] = d;
          }
        }
    }
  }

  __syncthreads();  // all es fragment reads done; safe to overlay
  float* redB = (float*)es;          // [2][128]
  float* redS = redB + 256;          // [2][128]
  int*   redI = (int*)(redS + 256);  // [2][128]
  int*   fIdx = redI + 256;          // [128]

  // cross-lane reduce over the 16 code-columns (xor masks 1,2,4,8)
#pragma unroll
  for (int mi = 0; mi < 4; ++mi)
#pragma unroll
    for (int r = 0; r < 4; ++r) {
      float b = best[mi][r], s2 = second[mi][r];
      int bi = bidx[mi][r];
#pragma unroll
      for (int m = 1; m <= 8; m <<= 1) {
        const float ob = __shfl_xor(b, m, 64);
        const float os = __shfl_xor(s2, m, 64);
        const int   oi = __shfl_xor(bi, m, 64);
        s2 = fminf(fminf(s2, os), fmaxf(b, ob));
        if (ob < b || (ob == b && oi < bi)) { b = ob; bi = oi; }
      }
      if (col == 0) {
        const int row = wr * 64 + mi * 16 + kq * 4 + r;
        redB[wc * 128 + row] = b; redS[wc * 128 + row] = s2;
        redI[wc * 128 + row] = bi;
      }
    }
  __syncthreads();
  if (tid < 128) {
    const float b0 = redB[tid], b1 = redB[128 + tid];
    const float s0 = redS[tid], s1 = redS[128 + tid];
    const int i0 = redI[tid], i1 = redI[128 + tid];
    const float s2 = fminf(fminf(s0, s1), fmaxf(b0, b1));
    float b; int bi;
    if (b1 < b0 || (b1 == b0 && i1 < i0)) { b = b1; bi = i1; } else { b = b0; bi = i0; }
    const int t = tokBase + tid;
    outIdxF[t] = (float)bi;
    bestDist[t] = b;
    fIdx[tid] = bi;
    atomicAdd(&hist[bi], 1);
    if (s2 - b < EPS) {
      const int p = atomicAdd(fixCount, 1);
      fixList[p] = t;
    }
  }
  __syncthreads();

  // -- fused gather: wave w copies rows w*32 .. w*32+31 (e rows from L2) --
  for (int i = 0; i < 32; ++i) {
    const int tl = w * 32 + i;
    const int id = fIdx[tl];
    const float4 q = reinterpret_cast<const float4*>(&e[id * DIM])[lane];
    reinterpret_cast<float4*>(&outQ[(tokBase + tl) * DIM])[lane] = q;
  }
}

// ---- exact fp32 rescan for near-tie tokens; patch idx/hist/outQ/dist ----
__global__ __launch_bounds__(256) void vq_fixup(
    const float* __restrict__ x, const float* __restrict__ e,
    const float* __restrict__ esq, const int* __restrict__ fixCount,
    const int* __restrict__ fixList, float* __restrict__ outIdxF,
    float* __restrict__ bestDist, float* __restrict__ outQ,
    int* __restrict__ hist) {
  const int n = *fixCount;
  __shared__ float xrow[256];
  __shared__ float rv[4];
  __shared__ int ri[4];
  __shared__ int sOld, sFi;
  const int tid = threadIdx.x;
  for (int it = blockIdx.x; it < n; it += gridDim.x) {
    const int t = fixList[it];
    __syncthreads();
    if (tid < 64) ((float4*)xrow)[tid] = ((const float4*)&x[t * DIM])[tid];
    __syncthreads();
    float bv = 3.4e38f; int bi = 0;
    for (int c = tid; c < KC; c += 256) {
      float s = 0.f;
#pragma unroll
      for (int d = 0; d < DIM; d += 4) {
        const float4 ev = *(const float4*)&e[c * DIM + d];
        s = fmaf(xrow[d], ev.x, s);
        s = fmaf(xrow[d + 1], ev.y, s);
        s = fmaf(xrow[d + 2], ev.z, s);
        s = fmaf(xrow[d + 3], ev.w, s);
      }
      const float dist = fmaf(-2.f, s, esq[c]);
      if (dist < bv) { bv = dist; bi = c; }  // c ascends per thread
    }
#pragma unroll
    for (int m = 1; m <= 32; m <<= 1) {
      const float ob = __shfl_xor(bv, m, 64);
      const int oi = __shfl_xor(bi, m, 64);
      if (ob < bv || (ob == bv && oi < bi)) { bv = ob; bi = oi; }
    }
    const int lane = tid & 63, wv = tid >> 6;
    if (lane == 0) { rv[wv] = bv; ri[wv] = bi; }
    __syncthreads();
    if (tid == 0) {
      float fb = rv[0]; int fi = ri[0];
      for (int k = 1; k < 4; ++k)
        if (rv[k] < fb || (rv[k] == fb && ri[k] < fi)) { fb = rv[k]; fi = ri[k]; }
      sOld = (int)outIdxF[t];
      sFi = fi;
      bestDist[t] = fb;  // exact distance for loss
      if (fi != sOld) {
        atomicSub(&hist[sOld], 1);
        atomicAdd(&hist[fi], 1);
        outIdxF[t] = (float)fi;
      }
    }
    __syncthreads();
    if (sFi != sOld) outQ[t * DIM + tid] = e[sFi * DIM + tid];
    __syncthreads();
  }
}

// ---- final scalars: loss from xsq+bestDist; perplexity from hist ----
__global__ __launch_bounds__(1024) void vq_final(
    const int* __restrict__ hist, const float* __restrict__ xsq,
    const float* __restrict__ bestDist, float* __restrict__ outLoss,
    float* __restrict__ outPerp) {
  const int tid = threadIdx.x;
  float ls = 0.f;
  for (int i = 0; i < 64; ++i) {
    const int t = tid + i * 1024;
    ls += xsq[t] + bestDist[t];
  }
  const float p = (float)hist[tid] * (1.f / 65536.f);
  float ent = p * logf(p + 1e-10f);
#pragma unroll
  for (int o = 32; o > 0; o >>= 1) {
    ls += __shfl_down(ls, o, 64);
    ent += __shfl_down(ent, o, 64);
  }
  __shared__ float lbuf[16], ebuf[16];
  const int lane = tid & 63, wv = tid >> 6;
  if (lane == 0) { lbuf[wv] = ls; ebuf[wv] = ent; }
  __syncthreads();
  if (tid == 0) {
    float L = 0.f, E = 0.f;
    for (int i = 0; i < 16; ++i) { L += lbuf[i]; E += ebuf[i]; }
    *outLoss = 0.25f * (L / 16777216.f);
    *outPerp = expf(-E);
  }
}

extern "C" void kernel_launch(void* const* d_in, const int* in_sizes, int n_in,
                              void* d_out, int out_size, void* d_ws, size_t ws_size,
                              hipStream_t stream) {
  const float* x = (const float*)d_in[0];  // [65536, 256]
  const float* e = (const float*)d_in[1];  // [1024, 256]
  float* out = (float*)d_out;
  float* outQ = out;                 // 16777216 floats
  float* outLoss = out + 16777216;
  float* outPerp = out + 16777217;
  float* outIdxF = out + 16777218;   // 65536 floats

  char* ws = (char*)d_ws;
  int*   hist     = (int*)ws;                    // 4096 B
  float* esq      = (float*)(ws + 4096);         // 4096 B
  float* xsq      = (float*)(ws + 8192);         // 262144 B
  float* bestDist = (float*)(ws + 270336);       // 262144 B
  int*   fixCount = (int*)(ws + 532480);         // 16 B
  int*   fixList  = (int*)(ws + 532496);         // 262144 B (+pad)
  unsigned short* e_f16 = (unsigned short*)(ws + 794640);  // 524288 B
  // total ws use ~1.32 MB

  vq_prep_e<<<KC / 4, 256, 0, stream>>>(e, e_f16, esq, hist, fixCount);
  vq_argmin_fused<<<NTOK / 128, 256, 0, stream>>>(
      x, e_f16, e, esq, outIdxF, outQ, bestDist, xsq, hist, fixCount, fixList);
  vq_fixup<<<256, 256, 0, stream>>>(x, e, esq, fixCount, fixList, outIdxF,
                                    bestDist, outQ, hist);
  vq_final<<<1, 1024, 0, stream>>>(hist, xsq, bestDist, outLoss, outPerp);
}

// Round 5
// 198.036 us; speedup vs baseline: 1.4865x; 1.0339x over previous
//
#include <hip/hip_runtime.h>

#define NTOK 65536
#define DIM 256
#define KC 1024
#define EPS 0.08f

typedef __attribute__((ext_vector_type(8))) _Float16 f16x8;
typedef __attribute__((ext_vector_type(4))) float f32x4;

static __device__ __forceinline__ unsigned short f16bits(float f) {
  _Float16 h = (_Float16)f;
  return __builtin_bit_cast(unsigned short, h);
}
static __device__ __forceinline__ void gload16(const void* g, void* l) {
  __builtin_amdgcn_global_load_lds(
      (const __attribute__((address_space(1))) unsigned int*)g,
      (__attribute__((address_space(3))) unsigned int*)l, 16, 0, 0);
}

// ---- e: fp32 -> fp16 swizzled global + esq; zero hist/fixCount ----
// Global image per row: 512 B = 4 slices of 128 B; within slice byte
// b holds k with b = ((k&63)*2) ^ ((row&7)<<4), slice = k>>6.
__global__ __launch_bounds__(256) void vq_prep_e(const float* __restrict__ e,
                                                 unsigned short* __restrict__ eg,
                                                 float* __restrict__ esq,
                                                 int* __restrict__ hist,
                                                 int* __restrict__ fixCount) {
  const int w = threadIdx.x >> 6, l = threadIdx.x & 63;
  const int t = blockIdx.x * 4 + w;
  const float4 v = *reinterpret_cast<const float4*>(&e[t * DIM + l * 4]);
  ushort4 o;
  o.x = f16bits(v.x); o.y = f16bits(v.y); o.z = f16bits(v.z); o.w = f16bits(v.w);
  const int addr = t * 512 + ((l >> 4) << 7) + ((((l & 15) * 8) ^ ((t & 7) << 4)));
  *reinterpret_cast<ushort4*>((char*)eg + addr) = o;
  float s = v.x * v.x + v.y * v.y + v.z * v.z + v.w * v.w;
#pragma unroll
  for (int o2 = 32; o2 > 0; o2 >>= 1) s += __shfl_down(s, o2, 64);
  if (l == 0) esq[t] = s;
  if (blockIdx.x < 4) hist[blockIdx.x * 256 + threadIdx.x] = 0;
  if (blockIdx.x == 0 && threadIdx.x == 0) *fixCount = 0;
}

// ---- fused: x-in-regs + pipelined e-staging + MFMA + argmin + gather ----
__global__ __launch_bounds__(256, 2) void vq_argmin_fused(
    const float* __restrict__ x, const unsigned short* __restrict__ eg,
    const float* __restrict__ e, const float* __restrict__ esq,
    float* __restrict__ outIdxF, float* __restrict__ outQ,
    float* __restrict__ bestDist, float* __restrict__ xsq,
    int* __restrict__ hist, int* __restrict__ fixCount,
    int* __restrict__ fixList) {
  __shared__ unsigned short es[3 * 8192];  // 48 KB: 3 bufs x (128 codes x 64 k)
  __shared__ int fidx[128];

  const int tid = threadIdx.x, lane = tid & 63, w = tid >> 6;
  const int tokBase = blockIdx.x * 128;
  const int col = lane & 15, kq = lane >> 4;

  // stage this wave's quarter (rows w*32..w*32+31) of tile (ct,kt) into buf b
  auto STAGE = [&](int tile, int b) {
    const int ct_ = tile >> 2, kt_ = tile & 3;
#pragma unroll
    for (int q = 0; q < 4; ++q) {
      const int r0 = w * 32 + q * 8;
      const int er = ct_ * 128 + r0 + (lane >> 3);
      gload16(&eg[er * DIM + kt_ * 64 + (lane & 7) * 8], &es[b * 8192 + r0 * 64]);
    }
  };

  STAGE(0, 0);

  // -- prologue: x -> registers in A-fragment layout; per-token xsq --
  // lane holds x[w*32 + m*16 + col][s*32 + kq*8 + j], j=0..7, as f16
  f16x8 a[2][8];
  float sqm[2] = {0.f, 0.f};
#pragma unroll
  for (int m = 0; m < 2; ++m) {
#pragma unroll
    for (int s = 0; s < 8; ++s) {
      const float* xp =
          &x[(tokBase + w * 32 + m * 16 + col) * DIM + s * 32 + kq * 8];
      const float4 v0 = *reinterpret_cast<const float4*>(xp);
      const float4 v1 = *reinterpret_cast<const float4*>(xp + 4);
      a[m][s][0] = (_Float16)v0.x; a[m][s][1] = (_Float16)v0.y;
      a[m][s][2] = (_Float16)v0.z; a[m][s][3] = (_Float16)v0.w;
      a[m][s][4] = (_Float16)v1.x; a[m][s][5] = (_Float16)v1.y;
      a[m][s][6] = (_Float16)v1.z; a[m][s][7] = (_Float16)v1.w;
      sqm[m] += v0.x * v0.x + v0.y * v0.y + v0.z * v0.z + v0.w * v0.w +
                v1.x * v1.x + v1.y * v1.y + v1.z * v1.z + v1.w * v1.w;
    }
  }
#pragma unroll
  for (int m = 0; m < 2; ++m) {
    sqm[m] += __shfl_xor(sqm[m], 16, 64);
    sqm[m] += __shfl_xor(sqm[m], 32, 64);
  }
  if (lane < 16) {
    xsq[tokBase + w * 32 + lane] = sqm[0];
    xsq[tokBase + w * 32 + 16 + lane] = sqm[1];
  }

  float best[2][4], second[2][4];
  int bidx[2][4];
#pragma unroll
  for (int mi = 0; mi < 2; ++mi)
#pragma unroll
    for (int r = 0; r < 4; ++r) {
      best[mi][r] = 3.4e38f; second[mi][r] = 3.4e38f; bidx[mi][r] = 0;
    }

  for (int ct = 0; ct < 8; ++ct) {
    f32x4 acc[2][8];
#pragma unroll
    for (int mi = 0; mi < 2; ++mi)
#pragma unroll
      for (int nj = 0; nj < 8; ++nj) acc[mi][nj] = (f32x4){0.f, 0.f, 0.f, 0.f};

#pragma unroll
    for (int kt = 0; kt < 4; ++kt) {
      const int tile = ct * 4 + kt;
      if (tile < 31) {  // uniform branch
        STAGE(tile + 1, (tile + 1) % 3);
        asm volatile("s_waitcnt vmcnt(4)" ::: "memory");  // tile landed
      } else {
        asm volatile("s_waitcnt vmcnt(0)" ::: "memory");
      }
      __builtin_amdgcn_s_barrier();  // raw: does NOT drain in-flight loads
      asm volatile("" ::: "memory");

      const char* bb = (const char*)es + (tile % 3) * 16384;
#pragma unroll
      for (int ks = 0; ks < 2; ++ks) {
        const int kb = ks * 64 + kq * 16;
        f16x8 bfr[8];
#pragma unroll
        for (int nj = 0; nj < 8; ++nj)
          bfr[nj] = *reinterpret_cast<const f16x8*>(
              bb + (nj * 16 + col) * 128 + (kb ^ ((col & 7) << 4)));
#pragma unroll
        for (int mi = 0; mi < 2; ++mi)
#pragma unroll
          for (int nj = 0; nj < 8; ++nj)
            acc[mi][nj] = __builtin_amdgcn_mfma_f32_16x16x32_f16(
                a[mi][kt * 2 + ks], bfr[nj], acc[mi][nj], 0, 0, 0);
      }
    }

    // distances for this 128-code chunk; codes ascend per lane over (ct, nj)
#pragma unroll
    for (int nj = 0; nj < 8; ++nj) {
      const int code = ct * 128 + nj * 16 + col;
      const float sqv = esq[code];
#pragma unroll
      for (int mi = 0; mi < 2; ++mi)
#pragma unroll
        for (int r = 0; r < 4; ++r) {
          const float d = fmaf(-2.f, acc[mi][nj][r], sqv);
          if (d < best[mi][r]) {
            second[mi][r] = best[mi][r];
            best[mi][r] = d;
            bidx[mi][r] = code;
          } else if (d < second[mi][r]) {
            second[mi][r] = d;
          }
        }
    }
  }

  // wave-local cross-lane reduce over the 16 code-columns
#pragma unroll
  for (int mi = 0; mi < 2; ++mi)
#pragma unroll
    for (int r = 0; r < 4; ++r) {
      float b = best[mi][r], s2 = second[mi][r];
      int bi = bidx[mi][r];
#pragma unroll
      for (int m = 1; m <= 8; m <<= 1) {
        const float ob = __shfl_xor(b, m, 64);
        const float os = __shfl_xor(s2, m, 64);
        const int   oi = __shfl_xor(bi, m, 64);
        s2 = fminf(fminf(s2, os), fmaxf(b, ob));
        if (ob < b || (ob == b && oi < bi)) { b = ob; bi = oi; }
      }
      if (col == 0) {
        const int tl = w * 32 + mi * 16 + kq * 4 + r;
        const int t = tokBase + tl;
        outIdxF[t] = (float)bi;
        bestDist[t] = b;
        fidx[tl] = bi;
        atomicAdd(&hist[bi], 1);
        if (s2 - b < EPS) {
          const int p = atomicAdd(fixCount, 1);
          fixList[p] = t;
        }
      }
    }
  __syncthreads();

  // fused gather: wave w copies its 32 tokens (e rows from L2)
  for (int i = 0; i < 32; ++i) {
    const int id = fidx[w * 32 + i];
    const float4 q = reinterpret_cast<const float4*>(&e[id * DIM])[lane];
    reinterpret_cast<float4*>(&outQ[(tokBase + w * 32 + i) * DIM])[lane] = q;
  }
}

// ---- exact fp32 rescan for near-tie tokens; patch idx/hist/outQ/dist ----
__global__ __launch_bounds__(256) void vq_fixup(
    const float* __restrict__ x, const float* __restrict__ e,
    const float* __restrict__ esq, const int* __restrict__ fixCount,
    const int* __restrict__ fixList, float* __restrict__ outIdxF,
    float* __restrict__ bestDist, float* __restrict__ outQ,
    int* __restrict__ hist) {
  const int n = *fixCount;
  __shared__ float xrow[256];
  __shared__ float rv[4];
  __shared__ int ri[4];
  __shared__ int sOld, sFi;
  const int tid = threadIdx.x;
  for (int it = blockIdx.x; it < n; it += gridDim.x) {
    const int t = fixList[it];
    __syncthreads();
    if (tid < 64) ((float4*)xrow)[tid] = ((const float4*)&x[t * DIM])[tid];
    __syncthreads();
    float bv = 3.4e38f; int bi = 0;
    for (int c = tid; c < KC; c += 256) {
      float s = 0.f;
#pragma unroll
      for (int d = 0; d < DIM; d += 4) {
        const float4 ev = *(const float4*)&e[c * DIM + d];
        s = fmaf(xrow[d], ev.x, s);
        s = fmaf(xrow[d + 1], ev.y, s);
        s = fmaf(xrow[d + 2], ev.z, s);
        s = fmaf(xrow[d + 3], ev.w, s);
      }
      const float dist = fmaf(-2.f, s, esq[c]);
      if (dist < bv) { bv = dist; bi = c; }  // c ascends per thread
    }
#pragma unroll
    for (int m = 1; m <= 32; m <<= 1) {
      const float ob = __shfl_xor(bv, m, 64);
      const int oi = __shfl_xor(bi, m, 64);
      if (ob < bv || (ob == bv && oi < bi)) { bv = ob; bi = oi; }
    }
    const int lane = tid & 63, wv = tid >> 6;
    if (lane == 0) { rv[wv] = bv; ri[wv] = bi; }
    __syncthreads();
    if (tid == 0) {
      float fb = rv[0]; int fi = ri[0];
      for (int k = 1; k < 4; ++k)
        if (rv[k] < fb || (rv[k] == fb && ri[k] < fi)) { fb = rv[k]; fi = ri[k]; }
      sOld = (int)outIdxF[t];
      sFi = fi;
      bestDist[t] = fb;  // exact distance for loss
      if (fi != sOld) {
        atomicSub(&hist[sOld], 1);
        atomicAdd(&hist[fi], 1);
        outIdxF[t] = (float)fi;
      }
    }
    __syncthreads();
    if (sFi != sOld) outQ[t * DIM + tid] = e[sFi * DIM + tid];
    __syncthreads();
  }
}

// ---- final scalars: loss from xsq+bestDist; perplexity from hist ----
__global__ __launch_bounds__(1024) void vq_final(
    const int* __restrict__ hist, const float* __restrict__ xsq,
    const float* __restrict__ bestDist, float* __restrict__ outLoss,
    float* __restrict__ outPerp) {
  const int tid = threadIdx.x;
  float ls = 0.f;
  for (int i = 0; i < 64; ++i) {
    const int t = tid + i * 1024;
    ls += xsq[t] + bestDist[t];
  }
  const float p = (float)hist[tid] * (1.f / 65536.f);
  float ent = p * logf(p + 1e-10f);
#pragma unroll
  for (int o = 32; o > 0; o >>= 1) {
    ls += __shfl_down(ls, o, 64);
    ent += __shfl_down(ent, o, 64);
  }
  __shared__ float lbuf[16], ebuf[16];
  const int lane = tid & 63, wv = tid >> 6;
  if (lane == 0) { lbuf[wv] = ls; ebuf[wv] = ent; }
  __syncthreads();
  if (tid == 0) {
    float L = 0.f, E = 0.f;
    for (int i = 0; i < 16; ++i) { L += lbuf[i]; E += ebuf[i]; }
    *outLoss = 0.25f * (L / 16777216.f);
    *outPerp = expf(-E);
  }
}

extern "C" void kernel_launch(void* const* d_in, const int* in_sizes, int n_in,
                              void* d_out, int out_size, void* d_ws, size_t ws_size,
                              hipStream_t stream) {
  const float* x = (const float*)d_in[0];  // [65536, 256]
  const float* e = (const float*)d_in[1];  // [1024, 256]
  float* out = (float*)d_out;
  float* outQ = out;                 // 16777216 floats
  float* outLoss = out + 16777216;
  float* outPerp = out + 16777217;
  float* outIdxF = out + 16777218;   // 65536 floats

  char* ws = (char*)d_ws;
  int*   hist     = (int*)ws;                    // 4096 B
  float* esq      = (float*)(ws + 4096);         // 4096 B
  float* xsq      = (float*)(ws + 8192);         // 262144 B
  float* bestDist = (float*)(ws + 270336);       // 262144 B
  int*   fixCount = (int*)(ws + 532480);         // 16 B
  int*   fixList  = (int*)(ws + 532496);         // 262144 B (+pad)
  unsigned short* e_f16 = (unsigned short*)(ws + 794640);  // 524288 B

  vq_prep_e<<<KC / 4, 256, 0, stream>>>(e, e_f16, esq, hist, fixCount);
  vq_argmin_fused<<<NTOK / 128, 256, 0, stream>>>(
      x, e_f16, e, esq, outIdxF, outQ, bestDist, xsq, hist, fixCount, fixList);
  vq_fixup<<<256, 256, 0, stream>>>(x, e, esq, fixCount, fixList, outIdxF,
                                    bestDist, outQ, hist);
  vq_final<<<1, 1024, 0, stream>>>(hist, xsq, bestDist, outLoss, outPerp);
}